// Round 7
// baseline (104.790 us; speedup 1.0000x reference)
//
#include <hip/hip_runtime.h>

#define B_SZ 64
#define S_SZ 2048
#define RNN 1024
#define ATT 512
#define NCHUNK 32
#define CHUNK_S (S_SZ / NCHUNK)   // 64
#define KSPL 2                    // k-split halves for the h-GEMM

// ws layout in floats:
//   att_h_part: [KSPL][B][ATT]      off 0         (65536)
//   partials  : [B][NCHUNK][RNN]    off 65536     (2097152)
//   usum      : [B][NCHUNK]         off 2162688   (2048)
#define OFF_ATTHP  0
#define OFF_PART   65536
#define OFF_USUM   2162688

// tanh(x) = 1 - 2/(1 + 2^(x * 2/ln2))
__device__ __forceinline__ float fast_tanh(float x) {
    float t = __builtin_exp2f(x * 2.885390082f);
    return 1.0f - 2.0f * __builtin_amdgcn_rcpf(t + 1.0f);
}

// --- Kernel 0: att_h_part[ks][b][j] = h[b, ks*512..+512) . W_h[j, same) ---
// grid (4, KSPL, B), block 128; 4 independent accumulators
__global__ __launch_bounds__(128) void k_atth(const float* __restrict__ h,
                                              const float* __restrict__ Wh,
                                              float* __restrict__ att_h_part) {
    int b  = blockIdx.z;
    int ks = blockIdx.y;
    int j  = blockIdx.x * 128 + threadIdx.x;   // 0..511
    int kbase = ks * (RNN / KSPL);

    __shared__ float hs[RNN / KSPL];           // 512 floats
    for (int i = threadIdx.x; i < RNN / KSPL; i += 128)
        hs[i] = h[(size_t)b * RNN + kbase + i];
    __syncthreads();

    const float4* w4 = (const float4*)(Wh + (size_t)j * RNN + kbase);
    const float4* h4 = (const float4*)hs;
    float a0 = 0.f, a1 = 0.f, a2 = 0.f, a3 = 0.f;
    #pragma unroll 4
    for (int k = 0; k < (RNN / KSPL) / 4; k += 4) {
        float4 w, hv;
        w = w4[k + 0]; hv = h4[k + 0];
        a0 += w.x * hv.x + w.y * hv.y + w.z * hv.z + w.w * hv.w;
        w = w4[k + 1]; hv = h4[k + 1];
        a1 += w.x * hv.x + w.y * hv.y + w.z * hv.z + w.w * hv.w;
        w = w4[k + 2]; hv = h4[k + 2];
        a2 += w.x * hv.x + w.y * hv.y + w.z * hv.z + w.w * hv.w;
        w = w4[k + 3]; hv = h4[k + 3];
        a3 += w.x * hv.x + w.y * hv.y + w.z * hv.z + w.w * hv.w;
    }
    att_h_part[((size_t)ks * B_SZ + b) * ATT + j] = (a0 + a1) + (a2 + a3);
}

// --- Fused kernel with mask-compaction (padded to multiples of 8):
//   phase 1: u_c[k] = exp(w_a . tanh(p[b,row_k,:]+att_h[b,:]) + b_a), active rows
//   phase 2: partials[b,c,:] = sum_k u_c[k]*att_feats[b,row_k,:]; usum[b,c]=sum u_c
// grid (NCHUNK, B), block 256 = 4 waves
__global__ __launch_bounds__(256, 8) void k_fused(const float* __restrict__ p,
                                                  const float* __restrict__ att_h_part,
                                                  const float* __restrict__ bh,
                                                  const float* __restrict__ w_a,
                                                  const float* __restrict__ b_a,
                                                  const int* __restrict__ mask,
                                                  const float* __restrict__ feats,
                                                  float* __restrict__ partials,
                                                  float* __restrict__ usum) {
    int c = blockIdx.x;
    int b = blockIdx.y;
    int t = threadIdx.x;
    int s0 = c * CHUNK_S;

    __shared__ float ah[ATT];
    __shared__ float wa[ATT];
    __shared__ float u_c[CHUNK_S];     // zeros beyond nact (incl. padding slots)
    __shared__ int   active[CHUNK_S];  // compacted active rows, then dummy zeros
    __shared__ int   nact_s;

    const float* ph0 = att_h_part + (size_t)b * ATT;
    const float* ph1 = att_h_part + ((size_t)B_SZ + b) * ATT;
    for (int i = t; i < ATT; i += 256) {
        ah[i] = ph0[i] + ph1[i] + bh[i];
        wa[i] = w_a[i];
    }
    if (t < CHUNK_S) {                 // exactly wave 0; t == lane
        u_c[t] = 0.f;
        int m = mask[(size_t)b * S_SZ + s0 + t];
        unsigned long long bal = __ballot(m != 0);
        int na = (int)__popcll(bal);
        unsigned long long below = (1ULL << (unsigned)t) - 1ULL;
        if (m) {
            active[__popcll(bal & below)] = t;
        } else {
            active[na + __popcll((~bal) & below)] = 0;   // dummy slot, weight 0
        }
        if (t == 0) nact_s = na;
    }
    __syncthreads();
    int nact = nact_s;
    int n8 = (nact + 7) & ~7;

    int wave = t >> 6;
    int lane = t & 63;
    float ba = b_a[0];

    const float4* ah4 = (const float4*)ah;
    const float4* wa4 = (const float4*)wa;
    float4 a0 = ah4[lane];
    float4 a1 = ah4[64 + lane];
    float4 w0 = wa4[lane];
    float4 w1 = wa4[64 + lane];

    // phase 1: 2 rows per wave per iteration (4 loads in flight, 2 reduce chains)
    const float4* pbase = (const float4*)(p + ((size_t)b * S_SZ + s0) * ATT);
    for (int k0 = wave * 2; k0 < n8; k0 += 8) {
        int slA = active[k0];
        int slB = active[k0 + 1];
        const float4* pA = pbase + (size_t)slA * 128;
        const float4* pB = pbase + (size_t)slB * 128;
        float4 xa0 = pA[lane];
        float4 xa1 = pA[64 + lane];
        float4 xb0 = pB[lane];
        float4 xb1 = pB[64 + lane];

        float pa, pb;
        pa  = w0.x * fast_tanh(xa0.x + a0.x);
        pa += w0.y * fast_tanh(xa0.y + a0.y);
        pa += w0.z * fast_tanh(xa0.z + a0.z);
        pa += w0.w * fast_tanh(xa0.w + a0.w);
        pa += w1.x * fast_tanh(xa1.x + a1.x);
        pa += w1.y * fast_tanh(xa1.y + a1.y);
        pa += w1.z * fast_tanh(xa1.z + a1.z);
        pa += w1.w * fast_tanh(xa1.w + a1.w);

        pb  = w0.x * fast_tanh(xb0.x + a0.x);
        pb += w0.y * fast_tanh(xb0.y + a0.y);
        pb += w0.z * fast_tanh(xb0.z + a0.z);
        pb += w0.w * fast_tanh(xb0.w + a0.w);
        pb += w1.x * fast_tanh(xb1.x + a1.x);
        pb += w1.y * fast_tanh(xb1.y + a1.y);
        pb += w1.z * fast_tanh(xb1.z + a1.z);
        pb += w1.w * fast_tanh(xb1.w + a1.w);

        #pragma unroll
        for (int off = 32; off > 0; off >>= 1) {
            pa += __shfl_xor(pa, off, 64);
            pb += __shfl_xor(pb, off, 64);
        }

        if (lane == 0) {
            if (k0 < nact)
                u_c[k0] = __builtin_expf(fminf(pa + ba, 80.f));
            if (k0 + 1 < nact)
                u_c[k0 + 1] = __builtin_expf(fminf(pb + ba, 80.f));
        }
    }
    __syncthreads();

    // phase 2: 8-deep weighted gather-sum; thread t owns cols 4t..4t+3
    const float4* f4 = (const float4*)(feats + ((size_t)b * S_SZ + s0) * RNN);
    const int4*   act4 = (const int4*)active;
    const float4* uc4  = (const float4*)u_c;
    float4 acc = {0.f, 0.f, 0.f, 0.f};
    for (int k = 0; k < n8; k += 8) {
        int4  r0 = act4[(k >> 2) + 0];
        int4  r1 = act4[(k >> 2) + 1];
        float4 g0 = uc4[(k >> 2) + 0];
        float4 g1 = uc4[(k >> 2) + 1];
        float4 v0 = f4[(size_t)r0.x * 256 + t];
        float4 v1 = f4[(size_t)r0.y * 256 + t];
        float4 v2 = f4[(size_t)r0.z * 256 + t];
        float4 v3 = f4[(size_t)r0.w * 256 + t];
        float4 v4 = f4[(size_t)r1.x * 256 + t];
        float4 v5 = f4[(size_t)r1.y * 256 + t];
        float4 v6 = f4[(size_t)r1.z * 256 + t];
        float4 v7 = f4[(size_t)r1.w * 256 + t];
        acc.x += g0.x * v0.x; acc.y += g0.x * v0.y; acc.z += g0.x * v0.z; acc.w += g0.x * v0.w;
        acc.x += g0.y * v1.x; acc.y += g0.y * v1.y; acc.z += g0.y * v1.z; acc.w += g0.y * v1.w;
        acc.x += g0.z * v2.x; acc.y += g0.z * v2.y; acc.z += g0.z * v2.z; acc.w += g0.z * v2.w;
        acc.x += g0.w * v3.x; acc.y += g0.w * v3.y; acc.z += g0.w * v3.z; acc.w += g0.w * v3.w;
        acc.x += g1.x * v4.x; acc.y += g1.x * v4.y; acc.z += g1.x * v4.z; acc.w += g1.x * v4.w;
        acc.x += g1.y * v5.x; acc.y += g1.y * v5.y; acc.z += g1.y * v5.z; acc.w += g1.y * v5.w;
        acc.x += g1.z * v6.x; acc.y += g1.z * v6.y; acc.z += g1.z * v6.z; acc.w += g1.z * v6.w;
        acc.x += g1.w * v7.x; acc.y += g1.w * v7.y; acc.z += g1.w * v7.z; acc.w += g1.w * v7.w;
    }
    ((float4*)partials)[((size_t)b * NCHUNK + c) * 256 + t] = acc;

    if (wave == 0) {
        float s = u_c[lane];   // zeros beyond nact
        #pragma unroll
        for (int off = 32; off > 0; off >>= 1)
            s += __shfl_xor(s, off, 64);
        if (lane == 0) usum[(size_t)b * NCHUNK + c] = s;
    }
}

// --- Reduce: out[b,j] = (sum_c partials[b,c,j]) / (sum_c usum[b,c]) ---
// grid (RNN/256, B), block 256
__global__ __launch_bounds__(256) void k_reduce(const float* __restrict__ partials,
                                                const float* __restrict__ usum,
                                                float* __restrict__ out) {
    int b = blockIdx.y;
    int j = blockIdx.x * 256 + threadIdx.x;

    float tot = 0.f;
    #pragma unroll
    for (int c = 0; c < NCHUNK; ++c)
        tot += usum[(size_t)b * NCHUNK + c];   // block-uniform -> scalar loads

    float acc = 0.f;
    #pragma unroll 8
    for (int c = 0; c < NCHUNK; ++c)
        acc += partials[((size_t)b * NCHUNK + c) * RNN + j];

    out[(size_t)b * RNN + j] = acc / tot;
}

extern "C" void kernel_launch(void* const* d_in, const int* in_sizes, int n_in,
                              void* d_out, int out_size, void* d_ws, size_t ws_size,
                              hipStream_t stream) {
    const float* h         = (const float*)d_in[0];
    const float* att_feats = (const float*)d_in[1];
    const float* p_att     = (const float*)d_in[2];
    const int*   att_masks = (const int*)d_in[3];
    const float* W_h       = (const float*)d_in[4];
    const float* b_h       = (const float*)d_in[5];
    const float* w_a       = (const float*)d_in[6];
    const float* b_a       = (const float*)d_in[7];
    float* out = (float*)d_out;

    float* wsf = (float*)d_ws;
    float* att_h_part = wsf + OFF_ATTHP;
    float* partials   = wsf + OFF_PART;
    float* usum       = wsf + OFF_USUM;

    k_atth<<<dim3(4, KSPL, B_SZ), 128, 0, stream>>>(h, W_h, att_h_part);
    k_fused<<<dim3(NCHUNK, B_SZ), 256, 0, stream>>>(p_att, att_h_part, b_h, w_a, b_a,
                                                    att_masks, att_feats,
                                                    partials, usum);
    k_reduce<<<dim3(RNN / 256, B_SZ), 256, 0, stream>>>(partials, usum, out);
}